// Round 2
// baseline (571.092 us; speedup 1.0000x reference)
//
#include <hip/hip_runtime.h>

// Problem constants (from reference)
#define C_IN  8
#define H     32
#define W     32
#define C_OUT 16
#define KH    3
#define KW    3
#define OH    32
#define OW    32
#define N_IN  (C_IN * H * W)     // 8192
#define N_OUT (C_OUT * OH * OW)  // 16384
#define MROWS (N_IN + 1)         // 8193
#define MCOLS (N_OUT + 1)        // 16385

// M is 99.1% sparse: per row only C_OUT*KH*KW = 144 of 16385 entries can be
// nonzero. Strategy: float4 zero-fill the row at memset speed, __syncthreads,
// then scatter the <=144 nonzeros while the row is still in L2 (no extra HBM
// RMW). Rows start at row*16385 floats -> alignment rotates mod 4; peel
// p = (4 - row&3) & 3 head elements so vector stores are 16B-aligned.
__global__ __launch_bounds__(256) void build_M(const float* __restrict__ wts,
                                               const float* __restrict__ bias,
                                               float* __restrict__ M) {
    const int row = blockIdx.x;
    const int t   = threadIdx.x;
    float* __restrict__ Mrow = M + (size_t)row * MCOLS;

    if (row == N_IN) {
        // Bias row (row 8192: 16B-aligned since 8192%4==0). col = 1024*k + 4*t,
        // so channel index == k exactly (4*t <= 1020 < 1024).
        for (int k = 0; k < 16; ++k) {
            float b = bias[k];
            float4 v = make_float4(b, b, b, b);
            *(float4*)(Mrow + 1024 * k + 4 * t) = v;
        }
        if (t == 0) Mrow[N_OUT] = 1.0f;
        return;
    }

    // ---- phase 1: zero the row with aligned float4 stores ----
    const int p    = (4 - (row & 3)) & 3;          // head peel count
    const int Nf   = (MCOLS - p) >> 2;             // # aligned float4s (4095/4096)
    const int tail = MCOLS - p - 4 * Nf;           // trailing scalars (0..3)

    if (t < p)    Mrow[t] = 0.0f;
    if (t < tail) Mrow[p + 4 * Nf + t] = 0.0f;

    const float4 z = make_float4(0.0f, 0.0f, 0.0f, 0.0f);
    float* base = Mrow + p;                        // 16B-aligned
    #pragma unroll
    for (int k = 0; k < 16; ++k) {
        int idx = k * 256 + t;
        if (idx < Nf) *(float4*)(base + 4 * idx) = z;
    }

    // ---- phase 2: compute this thread's scatter target (overlap w/ stores) ----
    const int cin = row >> 10;
    const int iy  = (row >> 5) & 31;
    const int ix  = row & 31;

    int   scol = -1;
    float wv   = 0.0f;
    if (t < C_OUT * KH * KW) {
        int c   = t / 9;
        int rem = t - 9 * c;
        int kh  = rem / 3;
        int kw  = rem - 3 * kh;
        int i   = iy + 1 - kh;                     // output y receiving this tap
        int j   = ix + 1 - kw;
        if ((unsigned)i < 32u && (unsigned)j < 32u) {
            scol = c * 1024 + i * 32 + j;
            wv   = wts[c * 72 + cin * 9 + rem];    // w[c][cin][kh][kw]
        }
    }

    __syncthreads();   // zeros committed (vmcnt(0) before s_barrier) before scatter

    if (scol >= 0) Mrow[scol] = wv;
}

// Interval bounds: lo += min(w*l, w*u); hi += max(w*l, w*u) (+ bias).
// Term-identical to reference's pos/neg split.
__global__ __launch_bounds__(256) void bounds_kernel(const float* __restrict__ l_in,
                                                     const float* __restrict__ u_in,
                                                     const float* __restrict__ wts,
                                                     const float* __restrict__ bias,
                                                     float* __restrict__ out) {
    int tid = blockIdx.x * 256 + threadIdx.x;
    if (tid >= N_OUT) return;
    int c = tid >> 10;
    int i = (tid >> 5) & 31;
    int j = tid & 31;

    float lo = bias[c];
    float hi = lo;

    #pragma unroll
    for (int cin = 0; cin < C_IN; ++cin) {
        #pragma unroll
        for (int kh = 0; kh < KH; ++kh) {
            int iy = i - 1 + kh;
            if ((unsigned)iy >= (unsigned)H) continue;
            #pragma unroll
            for (int kw = 0; kw < KW; ++kw) {
                int ix = j - 1 + kw;
                if ((unsigned)ix >= (unsigned)W) continue;
                float w = wts[c * 72 + cin * 9 + kh * 3 + kw];
                int   r = cin * 1024 + iy * 32 + ix;
                float a = w * l_in[r];
                float b = w * u_in[r];
                lo += fminf(a, b);
                hi += fmaxf(a, b);
            }
        }
    }
    out[tid]         = lo;
    out[N_OUT + tid] = hi;
}

extern "C" void kernel_launch(void* const* d_in, const int* in_sizes, int n_in,
                              void* d_out, int out_size, void* d_ws, size_t ws_size,
                              hipStream_t stream) {
    const float* lower = (const float*)d_in[0];
    const float* upper = (const float*)d_in[1];
    const float* wts   = (const float*)d_in[2];
    const float* bias  = (const float*)d_in[3];

    float* out = (float*)d_out;
    float* M   = out + 2 * N_OUT;   // lo(16384) | hi(16384) | M(8193*16385)

    hipLaunchKernelGGL(bounds_kernel, dim3((N_OUT + 255) / 256), dim3(256), 0, stream,
                       lower, upper, wts, bias, out);
    hipLaunchKernelGGL(build_M, dim3(MROWS), dim3(256), 0, stream, wts, bias, M);
}

// Round 3
// 558.163 us; speedup vs baseline: 1.0232x; 1.0232x over previous
//
#include <hip/hip_runtime.h>

// Problem constants (from reference)
#define C_IN  8
#define H     32
#define W     32
#define C_OUT 16
#define KH    3
#define KW    3
#define OH    32
#define OW    32
#define N_IN  (C_IN * H * W)     // 8192
#define N_OUT (C_OUT * OH * OW)  // 16384
#define MROWS (N_IN + 1)         // 8193
#define MCOLS (N_OUT + 1)        // 16385

// Single fused kernel. Blocks 0..8191: build M row (direct streaming compute,
// no barrier after weight staging, no double-write). Block 8192: bias row.
// Blocks 8193..8256: interval bounds (lo/hi).
//
// Row-block math: row offset row*16385 rotates mod 4 -> peel p = (4-(row&3))&3
// head scalars so float4 stores are 16B-aligned. For thread t, vector element
// col = p + 4t + 1024k: i, j (hence kh, kw, validity, weight sub-index) are
// k-invariant; c == k (+carry for the one straddling lane). k-loop body is
// 4 predicated LDS reads + 1 aligned float4 store per 4KB stride.
__global__ __launch_bounds__(256) void fused_kernel(const float* __restrict__ l_in,
                                                    const float* __restrict__ u_in,
                                                    const float* __restrict__ wts,
                                                    const float* __restrict__ bias,
                                                    float* __restrict__ out,
                                                    float* __restrict__ M) {
    const int b = blockIdx.x;
    const int t = threadIdx.x;

    if (b < N_IN) {
        // ---------------- build one sparse row of M ----------------
        const int row = b;
        const int cin = row >> 10;
        const int iy  = (row >> 5) & 31;
        const int ix  = row & 31;

        __shared__ float ldsW[160];      // [0,144): w[c][cin][kh][kw]; [144,160): zeros
        if (t < 144) {
            int c = t / 9, r = t - 9 * c;
            ldsW[t] = wts[c * 72 + cin * 9 + r];
        } else if (t < 160) {
            ldsW[t] = 0.0f;              // safe slots for the carry-straddle OOB index
        }
        __syncthreads();

        float* __restrict__ Mrow = M + (size_t)row * MCOLS;
        const int p    = (4 - (row & 3)) & 3;
        const int Nf   = (MCOLS - p) >> 2;           // 4095 or 4096 aligned float4s
        const int tail = MCOLS - p - 4 * Nf;         // 0..3 trailing scalars

        // head peel: cols 0..p-1  (c=0, i=0, j=col)
        if (t < p) {
            int kh = iy + 1, kw = ix + 1 - t;
            bool ok = ((unsigned)kh < 3u) & ((unsigned)kw < 3u);
            Mrow[t] = ok ? ldsW[kh * 3 + kw] : 0.0f;
        }
        // tail peel (includes homogeneous col 16384 -> 0)
        if (t < tail) {
            int col = p + 4 * Nf + t;
            float v = 0.0f;
            if (col < N_OUT) {
                int c = col >> 10, i = (col >> 5) & 31, j = col & 31;
                int kh = iy + 1 - i, kw = ix + 1 - j;
                if (((unsigned)kh < 3u) & ((unsigned)kw < 3u)) v = ldsW[c * 9 + kh * 3 + kw];
            }
            Mrow[col] = v;
        }

        // per-lane k-invariants
        int  add9[4];                      // carry*9 + kh*3+kw  (LDS sub-index)
        bool okq[4];                       // tap validity
        int  klim[4];                      // c = k + carry must stay < 16
        const int e0 = p + 4 * t;          // 0..1023(+3)
        #pragma unroll
        for (int q = 0; q < 4; ++q) {
            int e     = e0 + q;            // <= 1026
            int carry = e >> 10;           // 0 or 1 (t=255 straddle lanes only)
            int em    = e & 1023;
            int i = em >> 5, j = em & 31;
            int kh = iy + 1 - i, kw = ix + 1 - j;
            bool ok = ((unsigned)kh < 3u) & ((unsigned)kw < 3u);
            okq[q]  = ok;
            add9[q] = carry * 9 + (ok ? kh * 3 + kw : 0);
            klim[q] = 16 - carry;
        }

        float* dst = Mrow + p + 4 * t;     // 16B-aligned
        #pragma unroll
        for (int k = 0; k < 16; ++k) {
            int idx = (k << 8) + t;
            if (idx < Nf) {
                float vv[4];
                #pragma unroll
                for (int q = 0; q < 4; ++q) {
                    float w = ldsW[k * 9 + add9[q]];          // max idx 152 < 160
                    vv[q] = (okq[q] & (k < klim[q])) ? w : 0.0f;
                }
                *(float4*)(dst + (k << 10)) = make_float4(vv[0], vv[1], vv[2], vv[3]);
            }
        }
        return;
    }

    if (b == N_IN) {
        // ---------------- bias row (row 8192, start 16B-aligned) ----------------
        float* __restrict__ Mrow = M + (size_t)N_IN * MCOLS;
        #pragma unroll
        for (int k = 0; k < 16; ++k) {
            float bv = bias[k];            // channel index == k exactly (4t <= 1020)
            *(float4*)(Mrow + (k << 10) + 4 * t) = make_float4(bv, bv, bv, bv);
        }
        if (t == 0) Mrow[N_OUT] = 1.0f;
        return;
    }

    // ---------------- interval bounds ----------------
    int tid = (b - (N_IN + 1)) * 256 + t;
    if (tid >= N_OUT) return;
    int c = tid >> 10;
    int i = (tid >> 5) & 31;
    int j = tid & 31;

    float lo = bias[c];
    float hi = lo;

    #pragma unroll
    for (int cin = 0; cin < C_IN; ++cin) {
        #pragma unroll
        for (int kh = 0; kh < KH; ++kh) {
            int iy = i - 1 + kh;
            if ((unsigned)iy >= (unsigned)H) continue;
            #pragma unroll
            for (int kw = 0; kw < KW; ++kw) {
                int ix = j - 1 + kw;
                if ((unsigned)ix >= (unsigned)W) continue;
                float w = wts[c * 72 + cin * 9 + kh * 3 + kw];
                int   r = cin * 1024 + iy * 32 + ix;
                float a = w * l_in[r];
                float bb = w * u_in[r];
                lo += fminf(a, bb);
                hi += fmaxf(a, bb);
            }
        }
    }
    out[tid]         = lo;
    out[N_OUT + tid] = hi;
}

extern "C" void kernel_launch(void* const* d_in, const int* in_sizes, int n_in,
                              void* d_out, int out_size, void* d_ws, size_t ws_size,
                              hipStream_t stream) {
    const float* lower = (const float*)d_in[0];
    const float* upper = (const float*)d_in[1];
    const float* wts   = (const float*)d_in[2];
    const float* bias  = (const float*)d_in[3];

    float* out = (float*)d_out;
    float* M   = out + 2 * N_OUT;   // lo(16384) | hi(16384) | M(8193*16385)

    const int grid = N_IN + 1 + (N_OUT + 255) / 256;   // 8193 + 64
    hipLaunchKernelGGL(fused_kernel, dim3(grid), dim3(256), 0, stream,
                       lower, upper, wts, bias, out, M);
}

// Round 5
// 558.055 us; speedup vs baseline: 1.0234x; 1.0002x over previous
//
#include <hip/hip_runtime.h>

// Problem constants (from reference)
#define C_IN  8
#define H     32
#define W     32
#define C_OUT 16
#define KH    3
#define KW    3
#define OH    32
#define OW    32
#define N_IN  (C_IN * H * W)     // 8192
#define N_OUT (C_OUT * OH * OW)  // 16384
#define MROWS (N_IN + 1)         // 8193
#define MCOLS (N_OUT + 1)        // 16385

#define ROWS_PER_BLOCK 4
#define N_ROW_BLOCKS   (N_IN / ROWS_PER_BLOCK)   // 2048
#define N_BOUND_BLOCKS 64

// Native vector type: __builtin_nontemporal_store requires a real vector,
// not HIP's float4 class type.
typedef float v4f __attribute__((ext_vector_type(4)));

// Single fused kernel, block roles ordered so the latency-bound bounds blocks
// dispatch FIRST and hide under the 537 MB store stream:
//   b in [0,64):        interval bounds (lo/hi)
//   b == 64:            bias row of M
//   b in [65, 65+2048): 4 consecutive M rows each (same cin within a group,
//                       since 1024 % 4 == 0) — weights staged to LDS once.
//
// Row math (verified r3): row offset row*16385 rotates mod 4 -> peel
// p = (4-(row&3))&3 head scalars so float4 stores are 16B-aligned. For thread
// t, vector element col = p + 4t + 1024k: kh/kw/validity/weight sub-index are
// k-invariant per lane; c == k (+carry for the one straddling lane). Inner
// loop: 4 predicated LDS broadcasts + 1 nontemporal v4f store per 4KB step.
__global__ __launch_bounds__(256) void fused_kernel(const float* __restrict__ l_in,
                                                    const float* __restrict__ u_in,
                                                    const float* __restrict__ wts,
                                                    const float* __restrict__ bias,
                                                    float* __restrict__ out,
                                                    float* __restrict__ M) {
    const int b = blockIdx.x;
    const int t = threadIdx.x;

    if (b < N_BOUND_BLOCKS) {
        // ---------------- interval bounds (dispatched first, hides in tail) ----
        int tid = b * 256 + t;
        int c = tid >> 10;
        int i = (tid >> 5) & 31;
        int j = tid & 31;

        float lo = bias[c];
        float hi = lo;

        #pragma unroll
        for (int cin = 0; cin < C_IN; ++cin) {
            #pragma unroll
            for (int kh = 0; kh < KH; ++kh) {
                int iy = i - 1 + kh;
                if ((unsigned)iy >= (unsigned)H) continue;
                #pragma unroll
                for (int kw = 0; kw < KW; ++kw) {
                    int ix = j - 1 + kw;
                    if ((unsigned)ix >= (unsigned)W) continue;
                    float w = wts[c * 72 + cin * 9 + kh * 3 + kw];
                    int   r = cin * 1024 + iy * 32 + ix;
                    float a  = w * l_in[r];
                    float bb = w * u_in[r];
                    lo += fminf(a, bb);
                    hi += fmaxf(a, bb);
                }
            }
        }
        out[tid]         = lo;
        out[N_OUT + tid] = hi;
        return;
    }

    if (b == N_BOUND_BLOCKS) {
        // ---------------- bias row (row 8192, start 16B-aligned) ----------------
        float* __restrict__ Mrow = M + (size_t)N_IN * MCOLS;
        #pragma unroll
        for (int k = 0; k < 16; ++k) {
            float bv = bias[k];            // channel index == k exactly (4t <= 1020)
            v4f v = {bv, bv, bv, bv};
            __builtin_nontemporal_store(v, (v4f*)(Mrow + (k << 10) + 4 * t));
        }
        if (t == 0) Mrow[N_OUT] = 1.0f;
        return;
    }

    // ---------------- 4 sparse rows of M per block ----------------
    const int g   = b - (N_BOUND_BLOCKS + 1);   // 0..2047
    const int r0  = g * ROWS_PER_BLOCK;
    const int cin = r0 >> 10;                   // same for all 4 rows

    __shared__ float ldsW[160];      // [0,144): w[c][cin][kh][kw]; [144,160): zeros
    if (t < 144) {
        int c = t / 9, r = t - 9 * c;
        ldsW[t] = wts[c * 72 + cin * 9 + r];
    } else if (t < 160) {
        ldsW[t] = 0.0f;              // safe slots for the carry-straddle OOB index
    }
    __syncthreads();

    for (int rr = 0; rr < ROWS_PER_BLOCK; ++rr) {
        const int row = r0 + rr;
        const int iy  = (row >> 5) & 31;
        const int ix  = row & 31;

        float* __restrict__ Mrow = M + (size_t)row * MCOLS;
        const int p    = (4 - (row & 3)) & 3;
        const int Nf   = (MCOLS - p) >> 2;           // 4095 or 4096 aligned float4s
        const int tail = MCOLS - p - 4 * Nf;         // 0..3 trailing scalars

        // head peel: cols 0..p-1  (c=0, i=0, j=col)
        if (t < p) {
            int kh = iy + 1, kw = ix + 1 - t;
            bool ok = ((unsigned)kh < 3u) & ((unsigned)kw < 3u);
            Mrow[t] = ok ? ldsW[kh * 3 + kw] : 0.0f;
        }
        // tail peel (includes homogeneous col 16384 -> 0 when p==0)
        if (t < tail) {
            int col = p + 4 * Nf + t;
            float v = 0.0f;
            if (col < N_OUT) {
                int c = col >> 10, i = (col >> 5) & 31, j = col & 31;
                int kh = iy + 1 - i, kw = ix + 1 - j;
                if (((unsigned)kh < 3u) & ((unsigned)kw < 3u)) v = ldsW[c * 9 + kh * 3 + kw];
            }
            Mrow[col] = v;
        }

        // per-lane k-invariants
        int  add9[4];                      // carry*9 + kh*3+kw  (LDS sub-index)
        bool okq[4];                       // tap validity
        int  klim[4];                      // c = k + carry must stay < 16
        const int e0 = p + 4 * t;          // 0..1026
        #pragma unroll
        for (int q = 0; q < 4; ++q) {
            int e     = e0 + q;
            int carry = e >> 10;           // 0 or 1 (straddle lanes only)
            int em    = e & 1023;
            int i = em >> 5, j = em & 31;
            int kh = iy + 1 - i, kw = ix + 1 - j;
            bool ok = ((unsigned)kh < 3u) & ((unsigned)kw < 3u);
            okq[q]  = ok;
            add9[q] = carry * 9 + (ok ? kh * 3 + kw : 0);
            klim[q] = 16 - carry;
        }

        float* dst = Mrow + p + 4 * t;     // 16B-aligned
        #pragma unroll
        for (int k = 0; k < 16; ++k) {
            int idx = (k << 8) + t;
            if (idx < Nf) {
                float vv[4];
                #pragma unroll
                for (int q = 0; q < 4; ++q) {
                    float w = ldsW[k * 9 + add9[q]];          // max idx 152 < 160
                    vv[q] = (okq[q] & (k < klim[q])) ? w : 0.0f;
                }
                v4f v4 = {vv[0], vv[1], vv[2], vv[3]};
                __builtin_nontemporal_store(v4, (v4f*)(dst + (k << 10)));
            }
        }
    }
}

extern "C" void kernel_launch(void* const* d_in, const int* in_sizes, int n_in,
                              void* d_out, int out_size, void* d_ws, size_t ws_size,
                              hipStream_t stream) {
    const float* lower = (const float*)d_in[0];
    const float* upper = (const float*)d_in[1];
    const float* wts   = (const float*)d_in[2];
    const float* bias  = (const float*)d_in[3];

    float* out = (float*)d_out;
    float* M   = out + 2 * N_OUT;   // lo(16384) | hi(16384) | M(8193*16385)

    const int grid = N_BOUND_BLOCKS + 1 + N_ROW_BLOCKS;   // 64 + 1 + 2048 = 2113
    hipLaunchKernelGGL(fused_kernel, dim3(grid), dim3(256), 0, stream,
                       lower, upper, wts, bias, out, M);
}

// Round 6
// 557.261 us; speedup vs baseline: 1.0248x; 1.0014x over previous
//
#include <hip/hip_runtime.h>

// Problem constants (from reference)
#define C_IN  8
#define H     32
#define W     32
#define C_OUT 16
#define KH    3
#define KW    3
#define OH    32
#define OW    32
#define N_IN  (C_IN * H * W)     // 8192
#define N_OUT (C_OUT * OH * OW)  // 16384
#define MROWS (N_IN + 1)         // 8193
#define MCOLS (N_OUT + 1)        // 16385

#define ROWS_PER_BLOCK 4
#define N_ROW_BLOCKS   (N_IN / ROWS_PER_BLOCK)   // 2048
#define N_BOUND_BLOCKS 64

// Native vector type: __builtin_nontemporal_store requires a real vector type.
typedef float v4f __attribute__((ext_vector_type(4)));

// Block roles (bounds first so the latency-bound blocks hide under the store
// stream): [0,64) bounds | 64 bias row | [65,65+2048) 4 M-rows each.
//
// Row math (verified r3/r5): row offset row*16385 rotates mod 4 -> peel
// p=(4-(row&3))&3 head scalars so vector stores are 16B-aligned. For thread t,
// vector element col = p+4t+1024k: tap validity okq[] is k-INVARIANT, and the
// <=144 nonzero threads cluster in ~24 consecutive t -> typically 3 of 4 waves
// per row are all-zero. Those waves take a dependency-free fill loop (16
// back-to-back nt dwordx4 of a constant zero) — fill-kernel-identical issue
// pattern. k<15 stores are unconditional (idx<=3839 < Nf>=4095); only k=15
// needs the bound check.
__global__ __launch_bounds__(256) void fused_kernel(const float* __restrict__ l_in,
                                                    const float* __restrict__ u_in,
                                                    const float* __restrict__ wts,
                                                    const float* __restrict__ bias,
                                                    float* __restrict__ out,
                                                    float* __restrict__ M) {
    const int b = blockIdx.x;
    const int t = threadIdx.x;

    if (b < N_BOUND_BLOCKS) {
        // ---------------- interval bounds ----------------
        int tid = b * 256 + t;
        int c = tid >> 10;
        int i = (tid >> 5) & 31;
        int j = tid & 31;

        float lo = bias[c];
        float hi = lo;

        #pragma unroll
        for (int cin = 0; cin < C_IN; ++cin) {
            #pragma unroll
            for (int kh = 0; kh < KH; ++kh) {
                int iy = i - 1 + kh;
                if ((unsigned)iy >= (unsigned)H) continue;
                #pragma unroll
                for (int kw = 0; kw < KW; ++kw) {
                    int ix = j - 1 + kw;
                    if ((unsigned)ix >= (unsigned)W) continue;
                    float w = wts[c * 72 + cin * 9 + kh * 3 + kw];
                    int   r = cin * 1024 + iy * 32 + ix;
                    float a  = w * l_in[r];
                    float bb = w * u_in[r];
                    lo += fminf(a, bb);
                    hi += fmaxf(a, bb);
                }
            }
        }
        out[tid]         = lo;
        out[N_OUT + tid] = hi;
        return;
    }

    if (b == N_BOUND_BLOCKS) {
        // ---------------- bias row (row 8192, 16B-aligned start) ----------------
        float* __restrict__ Mrow = M + (size_t)N_IN * MCOLS;
        #pragma unroll
        for (int k = 0; k < 16; ++k) {
            float bv = bias[k];            // channel index == k exactly (4t <= 1020)
            v4f v = {bv, bv, bv, bv};
            __builtin_nontemporal_store(v, (v4f*)(Mrow + (k << 10) + 4 * t));
        }
        if (t == 0) Mrow[N_OUT] = 1.0f;
        return;
    }

    // ---------------- 4 sparse rows of M per block ----------------
    const int g   = b - (N_BOUND_BLOCKS + 1);   // 0..2047
    const int r0  = g * ROWS_PER_BLOCK;
    const int cin = r0 >> 10;                   // same for all 4 rows

    __shared__ float ldsW[160];      // [0,144): w[c][cin][kh][kw]; [144,160): zeros
    if (t < 144) {
        int c = t / 9, r = t - 9 * c;
        ldsW[t] = wts[c * 72 + cin * 9 + r];
    } else if (t < 160) {
        ldsW[t] = 0.0f;              // safe slots for the carry-straddle OOB index
    }
    __syncthreads();

    const v4f zero = {0.0f, 0.0f, 0.0f, 0.0f};

    for (int rr = 0; rr < ROWS_PER_BLOCK; ++rr) {
        const int row = r0 + rr;
        const int iy  = (row >> 5) & 31;
        const int ix  = row & 31;

        float* __restrict__ Mrow = M + (size_t)row * MCOLS;
        const int p    = (4 - (row & 3)) & 3;
        const int Nf   = (MCOLS - p) >> 2;           // 4095 or 4096 aligned float4s
        const int tail = MCOLS - p - 4 * Nf;         // 0..3 trailing scalars

        // head peel: cols 0..p-1  (c=0, i=0, j=col)
        if (t < p) {
            int kh = iy + 1, kw = ix + 1 - t;
            bool ok = ((unsigned)kh < 3u) & ((unsigned)kw < 3u);
            Mrow[t] = ok ? ldsW[kh * 3 + kw] : 0.0f;
        }
        // tail peel (includes homogeneous col 16384 -> 0 when p==0)
        if (t < tail) {
            int col = p + 4 * Nf + t;
            float v = 0.0f;
            if (col < N_OUT) {
                int c = col >> 10, i = (col >> 5) & 31, j = col & 31;
                int kh = iy + 1 - i, kw = ix + 1 - j;
                if (((unsigned)kh < 3u) & ((unsigned)kw < 3u)) v = ldsW[c * 9 + kh * 3 + kw];
            }
            Mrow[col] = v;
        }

        // per-lane k-invariants
        int  add9[4];                      // carry*9 + kh*3+kw  (LDS sub-index)
        bool okq[4];                       // tap validity (k-invariant!)
        int  klim[4];                      // c = k + carry must stay < 16
        const int e0 = p + 4 * t;          // 0..1026
        #pragma unroll
        for (int q = 0; q < 4; ++q) {
            int e     = e0 + q;
            int carry = e >> 10;           // 0 or 1 (straddle lanes only)
            int em    = e & 1023;
            int i = em >> 5, j = em & 31;
            int kh = iy + 1 - i, kw = ix + 1 - j;
            bool ok = ((unsigned)kh < 3u) & ((unsigned)kw < 3u);
            okq[q]  = ok;
            add9[q] = carry * 9 + (ok ? kh * 3 + kw : 0);
            klim[q] = 16 - carry;
        }

        float* dst = Mrow + p + 4 * t;     // 16B-aligned
        const bool lane_any = okq[0] | okq[1] | okq[2] | okq[3];

        if (!__any(lane_any)) {
            // ===== FAST PATH: whole wave writes zeros — dependency-free =====
            #pragma unroll
            for (int k = 0; k < 15; ++k)   // idx = k*256+t <= 3839 < Nf always
                __builtin_nontemporal_store(zero, (v4f*)(dst + (k << 10)));
            if ((15 << 8) + t < Nf)
                __builtin_nontemporal_store(zero, (v4f*)(dst + (15 << 10)));
        } else {
            // ===== SLOW PATH: compute values (<=2 waves per row land here) ====
            #pragma unroll
            for (int k = 0; k < 16; ++k) {
                if (k == 15 && (15 << 8) + t >= Nf) break;
                float vv[4];
                #pragma unroll
                for (int q = 0; q < 4; ++q) {
                    float w = ldsW[k * 9 + add9[q]];          // max idx 152 < 160
                    vv[q] = (okq[q] & (k < klim[q])) ? w : 0.0f;
                }
                v4f v4 = {vv[0], vv[1], vv[2], vv[3]};
                __builtin_nontemporal_store(v4, (v4f*)(dst + (k << 10)));
            }
        }
    }
}

extern "C" void kernel_launch(void* const* d_in, const int* in_sizes, int n_in,
                              void* d_out, int out_size, void* d_ws, size_t ws_size,
                              hipStream_t stream) {
    const float* lower = (const float*)d_in[0];
    const float* upper = (const float*)d_in[1];
    const float* wts   = (const float*)d_in[2];
    const float* bias  = (const float*)d_in[3];

    float* out = (float*)d_out;
    float* M   = out + 2 * N_OUT;   // lo(16384) | hi(16384) | M(8193*16385)

    const int grid = N_BOUND_BLOCKS + 1 + N_ROW_BLOCKS;   // 64 + 1 + 2048 = 2113
    hipLaunchKernelGGL(fused_kernel, dim3(grid), dim3(256), 0, stream,
                       lower, upper, wts, bias, out, M);
}

// Round 7
// 546.914 us; speedup vs baseline: 1.0442x; 1.0189x over previous
//
#include <hip/hip_runtime.h>

// Problem constants (from reference)
#define C_IN  8
#define H     32
#define W     32
#define C_OUT 16
#define KH    3
#define KW    3
#define OH    32
#define OW    32
#define N_IN  (C_IN * H * W)     // 8192
#define N_OUT (C_OUT * OH * OW)  // 16384
#define MROWS (N_IN + 1)         // 8193
#define MCOLS (N_OUT + 1)        // 16385

#define N_BOUND_BLOCKS 64
#define N_FLAT_BLOCKS  2048
// Flat region = rows 0..8191 of M: 8192*16385 = 134,225,920 floats = 33,556,480
// float4s exactly. Per grid-iteration the 2048 blocks write 524,288 float4s
// (8 MB window): 64 full iterations + 2,048 float4s tail (= blocks fb<8 fully).
#define ITER_F4     (N_FLAT_BLOCKS * 256)          // 524,288
#define N_FULL_ITER 64
#define TAIL_BLKS   8
// element step per iteration: 4*ITER_F4 = 2,097,152 = 127*16385 + 16257
#define STEP_ROW 127
#define STEP_COL 16257

typedef float v4f __attribute__((ext_vector_type(4)));

// Block roles: [0,64) bounds | 64 bias row | [65,65+2048) flat M writer.
// The flat writer's instantaneous footprint is one contiguous 8 MB window
// sliding over the 537 MB region (fill-kernel-like DRAM row locality),
// instead of 2048 concurrent streams spread over the whole buffer.
__global__ __launch_bounds__(256, 8) void fused_kernel(const float* __restrict__ l_in,
                                                       const float* __restrict__ u_in,
                                                       const float* __restrict__ wts,
                                                       const float* __restrict__ bias,
                                                       float* __restrict__ out,
                                                       float* __restrict__ M) {
    const int b = blockIdx.x;
    const int t = threadIdx.x;

    if (b < N_BOUND_BLOCKS) {
        // ---------------- interval bounds ----------------
        int tid = b * 256 + t;
        int c = tid >> 10;
        int i = (tid >> 5) & 31;
        int j = tid & 31;

        float lo = bias[c];
        float hi = lo;

        #pragma unroll
        for (int cin = 0; cin < C_IN; ++cin) {
            #pragma unroll
            for (int kh = 0; kh < KH; ++kh) {
                int iy = i - 1 + kh;
                if ((unsigned)iy >= (unsigned)H) continue;
                #pragma unroll
                for (int kw = 0; kw < KW; ++kw) {
                    int ix = j - 1 + kw;
                    if ((unsigned)ix >= (unsigned)W) continue;
                    float w = wts[c * 72 + cin * 9 + kh * 3 + kw];
                    int   r = cin * 1024 + iy * 32 + ix;
                    float a  = w * l_in[r];
                    float bb = w * u_in[r];
                    lo += fminf(a, bb);
                    hi += fmaxf(a, bb);
                }
            }
        }
        out[tid]         = lo;
        out[N_OUT + tid] = hi;
        return;
    }

    if (b == N_BOUND_BLOCKS) {
        // ---------------- bias row (row 8192, 16B-aligned start) ----------------
        float* __restrict__ Mrow = M + (size_t)N_IN * MCOLS;
        #pragma unroll
        for (int k = 0; k < 16; ++k) {
            float bv = bias[k];            // channel index == k exactly (4t <= 1020)
            v4f v = {bv, bv, bv, bv};
            __builtin_nontemporal_store(v, (v4f*)(Mrow + (k << 10) + 4 * t));
        }
        if (t == 0) Mrow[N_OUT] = 1.0f;
        return;
    }

    // ---------------- flat M writer (rows 0..8191) ----------------
    const int fb = b - (N_BOUND_BLOCKS + 1);      // 0..2047

    __shared__ float ldsW[C_OUT * C_IN * 9];      // full weight table, 1152 floats
    for (int s = t; s < C_OUT * C_IN * 9; s += 256) ldsW[s] = wts[s];
    __syncthreads();

    // initial (row, col) of this thread's first float4; e0 < 2^21 so the
    // >>14 approximation needs at most one correction (16385 = 2^14 + 1).
    const int f0 = fb * 256 + t;                  // float4 index in iteration 0
    const int e0 = f0 * 4;
    int row = e0 >> 14;
    int col = (e0 & 16383) - row;
    if (col < 0) { col += MCOLS; row -= 1; }

    float* dst = M + (size_t)e0;

    for (int n = 0; n < N_FULL_ITER + 1; ++n) {
        if (n == N_FULL_ITER && fb >= TAIL_BLKS) break;   // wave-uniform tail cut

        float vv[4];
        #pragma unroll
        for (int q = 0; q < 4; ++q) {
            int  cq    = col + q;
            bool carry = (cq >= MCOLS);           // straddle into next row (rare)
            int  cq2   = carry ? cq - MCOLS : cq;
            int  rq    = row + (carry ? 1 : 0);   // <= 8191 always (see tail math)
            int  cin   = rq >> 10;
            int  iy    = (rq >> 5) & 31;
            int  ix    = rq & 31;
            int  c     = cq2 >> 10;
            int  i     = (cq2 >> 5) & 31;
            int  j     = cq2 & 31;
            int  kh    = iy + 1 - i;
            int  kw    = ix + 1 - j;
            bool ok    = ((unsigned)kh < 3u) & ((unsigned)kw < 3u) & (cq2 < N_OUT);
            int  idx   = ok ? (c * 72 + cin * 9 + kh * 3 + kw) : 0;
            float w    = ldsW[idx];
            vv[q]      = ok ? w : 0.0f;
        }
        v4f v4 = {vv[0], vv[1], vv[2], vv[3]};
        __builtin_nontemporal_store(v4, (v4f*)dst);

        // advance one grid-iteration: +2,097,152 elements = +127 rows +16257 cols
        dst += (size_t)4 * ITER_F4;
        row += STEP_ROW;
        col += STEP_COL;
        if (col >= MCOLS) { col -= MCOLS; row += 1; }
    }
}

extern "C" void kernel_launch(void* const* d_in, const int* in_sizes, int n_in,
                              void* d_out, int out_size, void* d_ws, size_t ws_size,
                              hipStream_t stream) {
    const float* lower = (const float*)d_in[0];
    const float* upper = (const float*)d_in[1];
    const float* wts   = (const float*)d_in[2];
    const float* bias  = (const float*)d_in[3];

    float* out = (float*)d_out;
    float* M   = out + 2 * N_OUT;   // lo(16384) | hi(16384) | M(8193*16385)

    const int grid = N_BOUND_BLOCKS + 1 + N_FLAT_BLOCKS;   // 64 + 1 + 2048 = 2113
    hipLaunchKernelGGL(fused_kernel, dim3(grid), dim3(256), 0, stream,
                       lower, upper, wts, bias, out, M);
}

// Round 8
// 546.614 us; speedup vs baseline: 1.0448x; 1.0005x over previous
//
#include <hip/hip_runtime.h>

// Problem constants (from reference)
#define C_IN  8
#define H     32
#define W     32
#define C_OUT 16
#define KH    3
#define KW    3
#define OH    32
#define OW    32
#define N_IN  (C_IN * H * W)     // 8192
#define N_OUT (C_OUT * OH * OW)  // 16384
#define MROWS (N_IN + 1)         // 8193
#define MCOLS (N_OUT + 1)        // 16385

#define N_BOUND_BLOCKS 64
#define N_FLAT_BLOCKS  2048
// Flat region = rows 0..8191 of M: 8192*16385 = 134,225,920 floats = 33,556,480
// float4s exactly. Per grid-iteration the 2048 blocks write 524,288 float4s
// (8 MB window): 64 full iterations + 2,048 float4s tail (= blocks fb<8 fully).
#define ITER_F4     (N_FLAT_BLOCKS * 256)          // 524,288
#define N_FULL_ITER 64
#define TAIL_BLKS   8
// element step per iteration: 4*ITER_F4 = 2,097,152 = 127*16385 + 16257
#define STEP_ROW 127
#define STEP_COL 16257

typedef float v4f __attribute__((ext_vector_type(4)));

// Block roles — flat writer FIRST so the 2048 window blocks exactly fill the
// 2048 co-residency slots (8 blocks/CU x 256 CU) and the 8 MB sliding window
// is tight from cycle 0. Bias + bounds blocks (65 total, ~3 us) dispatch last
// and hide in the store-drain tail.
//   b in [0,2048):  flat M writer (rows 0..8191)
//   b == 2048:      bias row of M
//   b in (2048, 2048+64]: interval bounds
//
// Stores are PLAIN (not nontemporal): the rocclr fill kernel that reaches
// 6.35 TB/s on this exact buffer writes through L2 -> Infinity Cache -> HBM;
// nt bypasses that buffering and was the last structural difference.
__global__ __launch_bounds__(256, 8) void fused_kernel(const float* __restrict__ l_in,
                                                       const float* __restrict__ u_in,
                                                       const float* __restrict__ wts,
                                                       const float* __restrict__ bias,
                                                       float* __restrict__ out,
                                                       float* __restrict__ M) {
    const int b = blockIdx.x;
    const int t = threadIdx.x;

    if (b < N_FLAT_BLOCKS) {
        // ---------------- flat M writer (rows 0..8191) ----------------
        const int fb = b;

        __shared__ float ldsW[C_OUT * C_IN * 9];      // full weight table, 1152 floats
        for (int s = t; s < C_OUT * C_IN * 9; s += 256) ldsW[s] = wts[s];
        __syncthreads();

        // initial (row, col) of this thread's first float4; e0 < 2^21 so the
        // >>14 approximation needs at most one correction (16385 = 2^14 + 1).
        const int f0 = fb * 256 + t;                  // float4 index in iteration 0
        const int e0 = f0 * 4;
        int row = e0 >> 14;
        int col = (e0 & 16383) - row;
        if (col < 0) { col += MCOLS; row -= 1; }

        float* dst = M + (size_t)e0;

        for (int n = 0; n < N_FULL_ITER + 1; ++n) {
            if (n == N_FULL_ITER && fb >= TAIL_BLKS) break;   // wave-uniform tail cut

            float vv[4];
            #pragma unroll
            for (int q = 0; q < 4; ++q) {
                int  cq    = col + q;
                bool carry = (cq >= MCOLS);           // straddle into next row (rare)
                int  cq2   = carry ? cq - MCOLS : cq;
                int  rq    = row + (carry ? 1 : 0);   // <= 8191 always (tail math)
                int  cin   = rq >> 10;
                int  iy    = (rq >> 5) & 31;
                int  ix    = rq & 31;
                int  c     = cq2 >> 10;
                int  i     = (cq2 >> 5) & 31;
                int  j     = cq2 & 31;
                int  kh    = iy + 1 - i;
                int  kw    = ix + 1 - j;
                bool ok    = ((unsigned)kh < 3u) & ((unsigned)kw < 3u) & (cq2 < N_OUT);
                int  idx   = ok ? (c * 72 + cin * 9 + kh * 3 + kw) : 0;
                float w    = ldsW[idx];
                vv[q]      = ok ? w : 0.0f;
            }
            v4f v4 = {vv[0], vv[1], vv[2], vv[3]};
            *(v4f*)dst = v4;                          // plain store: through L2/L3

            // advance one grid-iteration: +2,097,152 elements = +127 rows +16257 cols
            dst += (size_t)4 * ITER_F4;
            row += STEP_ROW;
            col += STEP_COL;
            if (col >= MCOLS) { col -= MCOLS; row += 1; }
        }
        return;
    }

    if (b == N_FLAT_BLOCKS) {
        // ---------------- bias row (row 8192, 16B-aligned start) ----------------
        float* __restrict__ Mrow = M + (size_t)N_IN * MCOLS;
        #pragma unroll
        for (int k = 0; k < 16; ++k) {
            float bv = bias[k];            // channel index == k exactly (4t <= 1020)
            v4f v = {bv, bv, bv, bv};
            *(v4f*)(Mrow + (k << 10) + 4 * t) = v;
        }
        if (t == 0) Mrow[N_OUT] = 1.0f;
        return;
    }

    // ---------------- interval bounds (last 64 blocks, hide in tail) ----------
    int tid = (b - (N_FLAT_BLOCKS + 1)) * 256 + t;
    int c = tid >> 10;
    int i = (tid >> 5) & 31;
    int j = tid & 31;

    float lo = bias[c];
    float hi = lo;

    #pragma unroll
    for (int cin = 0; cin < C_IN; ++cin) {
        #pragma unroll
        for (int kh = 0; kh < KH; ++kh) {
            int iy = i - 1 + kh;
            if ((unsigned)iy >= (unsigned)H) continue;
            #pragma unroll
            for (int kw = 0; kw < KW; ++kw) {
                int ix = j - 1 + kw;
                if ((unsigned)ix >= (unsigned)W) continue;
                float w = wts[c * 72 + cin * 9 + kh * 3 + kw];
                int   r = cin * 1024 + iy * 32 + ix;
                float a  = w * l_in[r];
                float bb = w * u_in[r];
                lo += fminf(a, bb);
                hi += fmaxf(a, bb);
            }
        }
    }
    out[tid]         = lo;
    out[N_OUT + tid] = hi;
}

extern "C" void kernel_launch(void* const* d_in, const int* in_sizes, int n_in,
                              void* d_out, int out_size, void* d_ws, size_t ws_size,
                              hipStream_t stream) {
    const float* lower = (const float*)d_in[0];
    const float* upper = (const float*)d_in[1];
    const float* wts   = (const float*)d_in[2];
    const float* bias  = (const float*)d_in[3];

    float* out = (float*)d_out;
    float* M   = out + 2 * N_OUT;   // lo(16384) | hi(16384) | M(8193*16385)

    const int grid = N_FLAT_BLOCKS + 1 + N_BOUND_BLOCKS;   // 2048 + 1 + 64 = 2113
    hipLaunchKernelGGL(fused_kernel, dim3(grid), dim3(256), 0, stream,
                       lower, upper, wts, bias, out, M);
}

// Round 9
// 544.501 us; speedup vs baseline: 1.0488x; 1.0039x over previous
//
#include <hip/hip_runtime.h>

// Problem constants (from reference)
#define C_IN  8
#define H     32
#define W     32
#define C_OUT 16
#define KH    3
#define KW    3
#define OH    32
#define OW    32
#define N_IN  (C_IN * H * W)     // 8192
#define N_OUT (C_OUT * OH * OW)  // 16384
#define MROWS (N_IN + 1)         // 8193
#define MCOLS (N_OUT + 1)        // 16385

#define N_BOUND_BLOCKS 64
#define N_FLAT_BLOCKS  2048
// Flat region = rows 0..8191: 8192*16385 = 134,225,920 floats = 33,556,480
// float4s exactly. Per grid-iteration: 2048 blocks x 4 KB contiguous chunk
// each = 8 MB sliding window. 64 full iterations + 8-chunk tail (fb<8, n=64).
#define N_FULL_ITER 64
#define TAIL_BLKS   8
#define STEP_ELEMS  (N_FLAT_BLOCKS * 1024)   // 2,097,152 = 127*16385 + 16257
#define STEP_ROW    127
#define STEP_COL    16257

typedef float v4f __attribute__((ext_vector_type(4)));

// Block roles: [0,2048) flat M writer | 2048 bias row | (2048,2112] bounds.
//
// Flat writer, per iteration: block fb writes the contiguous 4 KB chunk at
// element E = (n*2048+fb)*1024 (thread t -> 4 floats at E+4t). Chunk lives in
// one row r (6% straddle into r+1, handled by a uniform per-thread select).
// Value is nonzero only where channel-local (i,j) is within the row's 3x3 tap
// window -> <= ~9 elements per chunk. Per-thread conservative ring-screen
// (~10 VALU) sends the ~97% provably-zero spans down a dependency-free
// zero-store fast path (no LDS reads, no selects); edge spans (row straddle /
// homogeneous col 16384) and possible-hit spans take the exact slow path.
// Screen correctness: span j's {j0..j0+3} mod 32 intersect {ix-1,ix,ix+1}
// => ((ix-j0+1)&31) <= 5; span i's subset of {i0,i0+1} intersect {iy-1..iy+1}
// => ((iy-i0+1)&31) <= 3. Both are per-dimension supersets of the exact hit
// condition (wrap cases only ADD false positives) -> zero false negatives.
__global__ __launch_bounds__(256, 8) void fused_kernel(const float* __restrict__ l_in,
                                                       const float* __restrict__ u_in,
                                                       const float* __restrict__ wts,
                                                       const float* __restrict__ bias,
                                                       float* __restrict__ out,
                                                       float* __restrict__ M) {
    const int b = blockIdx.x;
    const int t = threadIdx.x;

    if (b < N_FLAT_BLOCKS) {
        // ---------------- flat M writer (rows 0..8191) ----------------
        __shared__ float ldsW[C_OUT * C_IN * 9];      // full weight table
        for (int s = t; s < C_OUT * C_IN * 9; s += 256) ldsW[s] = wts[s];
        __syncthreads();

        // chunk-start (row, col) recurrence. E0 = b*1024 < 2^21, and
        // 16385 = 2^14+1 -> >>14 estimate needs at most one correction.
        const int E0 = b << 10;
        int r  = E0 >> 14;
        int c0 = (E0 & 16383) - r;
        if (c0 < 0) { c0 += MCOLS; r -= 1; }

        const int t4 = 4 * t;
        float* dst = M + (size_t)E0 + t4;
        const v4f zero = {0.0f, 0.0f, 0.0f, 0.0f};

        for (int n = 0; n < N_FULL_ITER + 1; ++n) {
            if (n == N_FULL_ITER && b >= TAIL_BLKS) break;   // wave-uniform tail

            // this thread's span start (may straddle into row r+1)
            int colt = c0 + t4;
            int rt   = r;
            if (colt >= MCOLS) { colt -= MCOLS; rt = r + 1; }

            const int iy = (rt >> 5) & 31;
            const int ix = rt & 31;
            const int j0 = colt & 31;
            const int i0 = (colt >> 5) & 31;

            const bool edge = (colt + 3 >= 16384);               // hom col / row straddle
            const bool jh   = (((ix - j0 + 1) & 31) <= 5);
            const bool ih   = (((iy - i0 + 1) & 31) <= 3);

            if (edge | (jh & ih)) {
                // ---- exact slow path (few threads per chunk) ----
                float vv[4];
                #pragma unroll
                for (int q = 0; q < 4; ++q) {
                    int  cq    = colt + q;
                    bool carry = (cq >= MCOLS);
                    int  cq2   = carry ? cq - MCOLS : cq;
                    int  rq    = rt + (carry ? 1 : 0);
                    int  cin   = rq >> 10;
                    int  iyq   = (rq >> 5) & 31;
                    int  ixq   = rq & 31;
                    int  c     = cq2 >> 10;
                    int  i     = (cq2 >> 5) & 31;
                    int  j     = cq2 & 31;
                    int  kh    = iyq + 1 - i;
                    int  kw    = ixq + 1 - j;
                    bool ok    = ((unsigned)kh < 3u) & ((unsigned)kw < 3u) & (cq2 < N_OUT);
                    int  idx   = ok ? (c * 72 + cin * 9 + kh * 3 + kw) : 0;
                    float w    = ldsW[idx];
                    vv[q]      = ok ? w : 0.0f;
                }
                v4f v4 = {vv[0], vv[1], vv[2], vv[3]};
                *(v4f*)dst = v4;
            } else {
                // ---- fast path: provably all-zero span ----
                *(v4f*)dst = zero;
            }

            dst += (size_t)STEP_ELEMS;
            c0  += STEP_COL;
            r   += STEP_ROW;
            if (c0 >= MCOLS) { c0 -= MCOLS; r += 1; }
        }
        return;
    }

    if (b == N_FLAT_BLOCKS) {
        // ---------------- bias row (row 8192, 16B-aligned start) ----------------
        float* __restrict__ Mrow = M + (size_t)N_IN * MCOLS;
        #pragma unroll
        for (int k = 0; k < 16; ++k) {
            float bv = bias[k];            // channel index == k exactly (4t <= 1020)
            v4f v = {bv, bv, bv, bv};
            *(v4f*)(Mrow + (k << 10) + 4 * t) = v;
        }
        if (t == 0) Mrow[N_OUT] = 1.0f;
        return;
    }

    // ---------------- interval bounds (last blocks, hide in tail) ----------
    int tid = (b - (N_FLAT_BLOCKS + 1)) * 256 + t;
    int c = tid >> 10;
    int i = (tid >> 5) & 31;
    int j = tid & 31;

    float lo = bias[c];
    float hi = lo;

    #pragma unroll
    for (int cin = 0; cin < C_IN; ++cin) {
        #pragma unroll
        for (int kh = 0; kh < KH; ++kh) {
            int iy = i - 1 + kh;
            if ((unsigned)iy >= (unsigned)H) continue;
            #pragma unroll
            for (int kw = 0; kw < KW; ++kw) {
                int ix = j - 1 + kw;
                if ((unsigned)ix >= (unsigned)W) continue;
                float w = wts[c * 72 + cin * 9 + kh * 3 + kw];
                int   r = cin * 1024 + iy * 32 + ix;
                float a  = w * l_in[r];
                float bb = w * u_in[r];
                lo += fminf(a, bb);
                hi += fmaxf(a, bb);
            }
        }
    }
    out[tid]         = lo;
    out[N_OUT + tid] = hi;
}

extern "C" void kernel_launch(void* const* d_in, const int* in_sizes, int n_in,
                              void* d_out, int out_size, void* d_ws, size_t ws_size,
                              hipStream_t stream) {
    const float* lower = (const float*)d_in[0];
    const float* upper = (const float*)d_in[1];
    const float* wts   = (const float*)d_in[2];
    const float* bias  = (const float*)d_in[3];

    float* out = (float*)d_out;
    float* M   = out + 2 * N_OUT;   // lo(16384) | hi(16384) | M(8193*16385)

    const int grid = N_FLAT_BLOCKS + 1 + N_BOUND_BLOCKS;   // 2048 + 1 + 64 = 2113
    hipLaunchKernelGGL(fused_kernel, dim3(grid), dim3(256), 0, stream,
                       lower, upper, wts, bias, out, M);
}